// Round 1
// baseline (97.071 us; speedup 1.0000x reference)
//
#include <hip/hip_runtime.h>
#include <hip/hip_bf16.h>

// Softmax over last axis: (1,16,2048,2048) fp32 -> fp32.
// 32768 rows x 2048 elems. One 256-thread block per row; 8 elems/thread in
// registers (2x float4). Memory-bound: target ~85us at 6.3 TB/s.

#define ROW_LEN 2048

__global__ __launch_bounds__(256) void softmax_rows_kernel(
    const float* __restrict__ in, float* __restrict__ out) {
    const size_t row = blockIdx.x;
    const float4* __restrict__ inr  = reinterpret_cast<const float4*>(in + row * ROW_LEN);
    float4* __restrict__ outr       = reinterpret_cast<float4*>(out + row * ROW_LEN);

    const int t    = threadIdx.x;
    const int lane = t & 63;
    const int wave = t >> 6;

    // Load 8 elements (two float4, coalesced: halves of the row)
    float4 a = inr[t];
    float4 b = inr[t + 256];

    // ---- max reduce ----
    float m = fmaxf(fmaxf(fmaxf(a.x, a.y), fmaxf(a.z, a.w)),
                    fmaxf(fmaxf(b.x, b.y), fmaxf(b.z, b.w)));
    #pragma unroll
    for (int off = 32; off > 0; off >>= 1)
        m = fmaxf(m, __shfl_xor(m, off));

    __shared__ float smax[4];
    __shared__ float ssum[4];
    if (lane == 0) smax[wave] = m;
    __syncthreads();
    m = fmaxf(fmaxf(smax[0], smax[1]), fmaxf(smax[2], smax[3]));

    // ---- exp + sum reduce ----
    a.x = __expf(a.x - m); a.y = __expf(a.y - m);
    a.z = __expf(a.z - m); a.w = __expf(a.w - m);
    b.x = __expf(b.x - m); b.y = __expf(b.y - m);
    b.z = __expf(b.z - m); b.w = __expf(b.w - m);

    float s = (a.x + a.y) + (a.z + a.w) + (b.x + b.y) + (b.z + b.w);
    #pragma unroll
    for (int off = 32; off > 0; off >>= 1)
        s += __shfl_xor(s, off);

    if (lane == 0) ssum[wave] = s;
    __syncthreads();
    s = (ssum[0] + ssum[1]) + (ssum[2] + ssum[3]);

    const float r = 1.0f / s;
    a.x *= r; a.y *= r; a.z *= r; a.w *= r;
    b.x *= r; b.y *= r; b.z *= r; b.w *= r;

    outr[t]       = a;
    outr[t + 256] = b;
}

extern "C" void kernel_launch(void* const* d_in, const int* in_sizes, int n_in,
                              void* d_out, int out_size, void* d_ws, size_t ws_size,
                              hipStream_t stream) {
    const float* x = (const float*)d_in[0];
    float* out = (float*)d_out;
    const int rows = in_sizes[0] / ROW_LEN;  // 32768
    hipLaunchKernelGGL(softmax_rows_kernel, dim3(rows), dim3(256), 0, stream, x, out);
}

// Round 3
// 83.015 us; speedup vs baseline: 1.1693x; 1.1693x over previous
//
#include <hip/hip_runtime.h>
#include <hip/hip_bf16.h>

// Softmax over last axis: (1,16,2048,2048) fp32 -> fp32.
// 32768 rows x 2048 elems. Grid-stride: 2048 blocks x 16 rows, 256 thr/block,
// 8 elems/thread in registers (2x float4). Non-temporal stores so the 256 MiB
// output stream doesn't evict the (L3-sized) input between graph replays.

#define ROW_LEN 2048
#define NBLOCKS 2048

typedef float f32x4 __attribute__((ext_vector_type(4)));  // native vec for nt-store

__global__ __launch_bounds__(256) void softmax_rows_kernel(
    const float* __restrict__ in, float* __restrict__ out, int rows) {
    const int t    = threadIdx.x;
    const int lane = t & 63;
    const int wave = t >> 6;

    __shared__ float smax[4];
    __shared__ float ssum[4];

    for (int row = blockIdx.x; row < rows; row += gridDim.x) {
        const f32x4* __restrict__ inr = reinterpret_cast<const f32x4*>(in + (size_t)row * ROW_LEN);
        f32x4* __restrict__ outr      = reinterpret_cast<f32x4*>(out + (size_t)row * ROW_LEN);

        // Load 8 elements (two float4, coalesced halves of the row)
        f32x4 a = inr[t];
        f32x4 b = inr[t + 256];

        // ---- max reduce (wave, then cross-wave via LDS) ----
        float m = fmaxf(fmaxf(fmaxf(a.x, a.y), fmaxf(a.z, a.w)),
                        fmaxf(fmaxf(b.x, b.y), fmaxf(b.z, b.w)));
        #pragma unroll
        for (int off = 32; off > 0; off >>= 1)
            m = fmaxf(m, __shfl_xor(m, off));

        if (lane == 0) smax[wave] = m;
        __syncthreads();                       // barrier 1
        m = fmaxf(fmaxf(smax[0], smax[1]), fmaxf(smax[2], smax[3]));

        // ---- exp + sum reduce ----
        a.x = __expf(a.x - m); a.y = __expf(a.y - m);
        a.z = __expf(a.z - m); a.w = __expf(a.w - m);
        b.x = __expf(b.x - m); b.y = __expf(b.y - m);
        b.z = __expf(b.z - m); b.w = __expf(b.w - m);

        float s = (a.x + a.y) + (a.z + a.w) + (b.x + b.y) + (b.z + b.w);
        #pragma unroll
        for (int off = 32; off > 0; off >>= 1)
            s += __shfl_xor(s, off);

        if (lane == 0) ssum[wave] = s;
        __syncthreads();                       // barrier 2
        s = (ssum[0] + ssum[1]) + (ssum[2] + ssum[3]);

        const float r = 1.0f / s;
        a.x *= r; a.y *= r; a.z *= r; a.w *= r;
        b.x *= r; b.y *= r; b.z *= r; b.w *= r;

        // Non-temporal stores: don't let the output stream evict the input
        // from L2/L3 (input is exactly L3-sized; replays can re-hit it).
        __builtin_nontemporal_store(a, &outr[t]);
        __builtin_nontemporal_store(b, &outr[t + 256]);
    }
}

extern "C" void kernel_launch(void* const* d_in, const int* in_sizes, int n_in,
                              void* d_out, int out_size, void* d_ws, size_t ws_size,
                              hipStream_t stream) {
    const float* x = (const float*)d_in[0];
    float* out = (float*)d_out;
    const int rows = in_sizes[0] / ROW_LEN;  // 32768
    hipLaunchKernelGGL(softmax_rows_kernel, dim3(NBLOCKS), dim3(256), 0, stream, x, out, rows);
}

// Round 4
// 82.773 us; speedup vs baseline: 1.1727x; 1.0029x over previous
//
#include <hip/hip_runtime.h>
#include <hip/hip_bf16.h>

// Softmax over last axis: (1,16,2048,2048) fp32 -> fp32.
// One ROW PER WAVE: 64 lanes x 32 elems (8x float4, interleaved so each load
// instruction covers 1KiB contiguous). No LDS, no __syncthreads -- reductions
// are in-register trees + 6 shfl_xor. Waves are fully independent streams.
// nt-stores keep the output from evicting the (L3-resident) input.

#define ROW_LEN 2048
#define NBLOCKS 2048

typedef float f32x4 __attribute__((ext_vector_type(4)));

__global__ __launch_bounds__(256) void softmax_wave_kernel(
    const float* __restrict__ in, float* __restrict__ out, int rows) {
    const int lane  = threadIdx.x & 63;
    const int wave  = threadIdx.x >> 6;
    const int gwave = blockIdx.x * 4 + wave;        // 4 waves/block
    const int nwaves = NBLOCKS * 4;

    for (int row = gwave; row < rows; row += nwaves) {
        const f32x4* __restrict__ inr = reinterpret_cast<const f32x4*>(in + (size_t)row * ROW_LEN);
        f32x4* __restrict__ outr      = reinterpret_cast<f32x4*>(out + (size_t)row * ROW_LEN);

        // 8 coalesced loads: lane + k*64 -> each instruction reads 1KiB contig.
        f32x4 v[8];
        #pragma unroll
        for (int k = 0; k < 8; ++k) v[k] = inr[lane + k * 64];

        // ---- max: in-register tree then 6-step wave butterfly ----
        float m = fmaxf(fmaxf(v[0].x, v[0].y), fmaxf(v[0].z, v[0].w));
        #pragma unroll
        for (int k = 1; k < 8; ++k)
            m = fmaxf(m, fmaxf(fmaxf(v[k].x, v[k].y), fmaxf(v[k].z, v[k].w)));
        #pragma unroll
        for (int off = 32; off > 0; off >>= 1)
            m = fmaxf(m, __shfl_xor(m, off));

        // ---- exp + sum ----
        float s = 0.0f;
        #pragma unroll
        for (int k = 0; k < 8; ++k) {
            v[k].x = __expf(v[k].x - m);
            v[k].y = __expf(v[k].y - m);
            v[k].z = __expf(v[k].z - m);
            v[k].w = __expf(v[k].w - m);
            s += (v[k].x + v[k].y) + (v[k].z + v[k].w);
        }
        #pragma unroll
        for (int off = 32; off > 0; off >>= 1)
            s += __shfl_xor(s, off);

        const float r = 1.0f / s;
        #pragma unroll
        for (int k = 0; k < 8; ++k) {
            v[k].x *= r; v[k].y *= r; v[k].z *= r; v[k].w *= r;
            __builtin_nontemporal_store(v[k], &outr[lane + k * 64]);
        }
    }
}

extern "C" void kernel_launch(void* const* d_in, const int* in_sizes, int n_in,
                              void* d_out, int out_size, void* d_ws, size_t ws_size,
                              hipStream_t stream) {
    const float* x = (const float*)d_in[0];
    float* out = (float*)d_out;
    const int rows = in_sizes[0] / ROW_LEN;  // 32768
    hipLaunchKernelGGL(softmax_wave_kernel, dim3(NBLOCKS), dim3(256), 0, stream, x, out, rows);
}

// Round 5
// 81.771 us; speedup vs baseline: 1.1871x; 1.0123x over previous
//
#include <hip/hip_runtime.h>
#include <hip/hip_bf16.h>

// Softmax over last axis: (1,16,2048,2048) fp32 -> fp32.
// One row per wave (64 lanes x 32 elems = 8x float4/lane), DEPTH-2 SOFTWARE
// PIPELINE: load row n+1's 8 KiB while reducing/exping row n, so each wave
// always has a full row of loads in flight (hides ~900cy HBM latency).
// Two named register buffers (static indexing only). nt-stores keep the
// output stream from evicting the (L3-resident) input between graph replays.

#define ROW_LEN 2048
#define NBLOCKS 2048
#define NWAVES  (NBLOCKS * 4)

typedef float f32x4 __attribute__((ext_vector_type(4)));

__device__ __forceinline__ void load_row(const float* __restrict__ in,
                                         int row, int lane, f32x4 (&v)[8]) {
    const f32x4* __restrict__ inr = reinterpret_cast<const f32x4*>(in + (size_t)row * ROW_LEN);
    #pragma unroll
    for (int k = 0; k < 8; ++k) v[k] = inr[lane + k * 64];
}

__device__ __forceinline__ void proc_row(float* __restrict__ out,
                                         int row, int lane, f32x4 (&v)[8]) {
    f32x4* __restrict__ outr = reinterpret_cast<f32x4*>(out + (size_t)row * ROW_LEN);

    float m = fmaxf(fmaxf(v[0].x, v[0].y), fmaxf(v[0].z, v[0].w));
    #pragma unroll
    for (int k = 1; k < 8; ++k)
        m = fmaxf(m, fmaxf(fmaxf(v[k].x, v[k].y), fmaxf(v[k].z, v[k].w)));
    #pragma unroll
    for (int off = 32; off > 0; off >>= 1)
        m = fmaxf(m, __shfl_xor(m, off));

    float s = 0.0f;
    #pragma unroll
    for (int k = 0; k < 8; ++k) {
        v[k].x = __expf(v[k].x - m);
        v[k].y = __expf(v[k].y - m);
        v[k].z = __expf(v[k].z - m);
        v[k].w = __expf(v[k].w - m);
        s += (v[k].x + v[k].y) + (v[k].z + v[k].w);
    }
    #pragma unroll
    for (int off = 32; off > 0; off >>= 1)
        s += __shfl_xor(s, off);

    const float r = 1.0f / s;
    #pragma unroll
    for (int k = 0; k < 8; ++k) {
        v[k].x *= r; v[k].y *= r; v[k].z *= r; v[k].w *= r;
        __builtin_nontemporal_store(v[k], &outr[lane + k * 64]);
    }
}

__global__ __launch_bounds__(256) void softmax_pipe_kernel(
    const float* __restrict__ in, float* __restrict__ out, int rows) {
    const int lane  = threadIdx.x & 63;
    const int gwave = blockIdx.x * 4 + (threadIdx.x >> 6);

    f32x4 va[8], vb[8];   // two named buffers -> static register indexing

    int row = gwave;
    if (row >= rows) return;
    load_row(in, row, lane, va);
    int next = row + NWAVES;

    while (true) {
        // phase A: prefetch into B, process A
        if (next >= rows) { proc_row(out, row, lane, va); break; }
        load_row(in, next, lane, vb);
        proc_row(out, row, lane, va);
        row = next; next += NWAVES;

        // phase B: prefetch into A, process B
        if (next >= rows) { proc_row(out, row, lane, vb); break; }
        load_row(in, next, lane, va);
        proc_row(out, row, lane, vb);
        row = next; next += NWAVES;
    }
}

extern "C" void kernel_launch(void* const* d_in, const int* in_sizes, int n_in,
                              void* d_out, int out_size, void* d_ws, size_t ws_size,
                              hipStream_t stream) {
    const float* x = (const float*)d_in[0];
    float* out = (float*)d_out;
    const int rows = in_sizes[0] / ROW_LEN;  // 32768
    hipLaunchKernelGGL(softmax_pipe_kernel, dim3(NBLOCKS), dim3(256), 0, stream, x, out, rows);
}